// Round 4
// baseline (7790.421 us; speedup 1.0000x reference)
//
#include <hip/hip_runtime.h>
#include <hip/hip_bf16.h>
#include <math.h>

// Sizes (fixed for this problem)
#define BB 4
#define TT 168
#define BT 672          // B*T
#define NN 16
#define FF 16
#define DD 4096         // N*N*F
#define HDH 512         // Hd
#define DFF 16384
#define HH 4            // heads
#define HDIM 1024       // D/H
#define UU 2            // sparse query count
#define WINW 25
#define XROWS 10752     // BT*N

// ---------------- ws layout (float element offsets) ----------------
#define OFF_TO   0
#define OFF_TD   1024
#define OFF_XM   2048
#define OFF_PM   3072
#define OFF_Y    4096
#define OFF_MG   2756608     // reused as attn-out (hbuf)
#define OFF_X    5509120
#define OFF_XN   8261632
#define OFF_Q    11014144    // also HOS, also FFN hidden
#define OFF_K    13766656
#define OFF_V    16519168    // also HDS
// total = 22024192 floats = 88.1 MB

// ---------------- helpers ----------------
__device__ __forceinline__ float block_sum256(float v) {
  __shared__ float sb[4];
  __syncthreads();
  for (int off = 32; off; off >>= 1) v += __shfl_down(v, off, 64);
  if ((threadIdx.x & 63) == 0) sb[threadIdx.x >> 6] = v;
  __syncthreads();
  return sb[0] + sb[1] + sb[2] + sb[3];
}

// ---------------- Chebyshev basis ----------------
__global__ void cheb_kernel(const float* __restrict__ Lo, const float* __restrict__ Ld,
                            float* __restrict__ To, float* __restrict__ Td) {
  int tid = threadIdx.x;
  int i = tid >> 4, j = tid & 15;
  float so = 0.f, sd = 0.f;
  for (int k = 0; k < 16; k++) {
    so += Lo[i * 16 + k] * Lo[k * 16 + j];
    sd += Ld[i * 16 + k] * Ld[k * 16 + j];
  }
  float I = (i == j) ? 1.0f : 0.0f;
  To[tid] = I;  To[256 + tid] = Lo[tid];  To[512 + tid] = 2.0f * so - I;
  Td[tid] = I;  Td[256 + tid] = Ld[tid];  Td[512 + tid] = 2.0f * sd - I;
}

// ---------------- TwoDGCN: MG[b,t,i,l,g]; also writes transposed view Ybuf ----------------
__global__ __launch_bounds__(256) void gcn_kernel(
    const float* __restrict__ M, const float* __restrict__ ToB,
    const float* __restrict__ TdB, const float* __restrict__ theta,
    float* __restrict__ MG, float* __restrict__ Ybuf) {
  int bt = blockIdx.x, tid = threadIdx.x;
  __shared__ float Msh[4096];   // [j][k][f]
  __shared__ float Rsh[4096];   // [j][l][f] for current c
  __shared__ float Tosh[768], Tdsh[768], thsh[2304];
  for (int e = 0; e < 16; e++) Msh[tid + e * 256] = M[(size_t)bt * 4096 + tid + e * 256];
  for (int e = 0; e < 3; e++) { Tosh[tid + e * 256] = ToB[tid + e * 256]; Tdsh[tid + e * 256] = TdB[tid + e * 256]; }
  for (int e = 0; e < 9; e++) thsh[tid + e * 256] = theta[tid + e * 256];
  __syncthreads();
  // transposed view: Ybuf[bt*4096 + n*256 + m*16 + f] = M[bt, m, n, f]
  for (int e = 0; e < 16; e++) {
    int idx = tid + e * 256;
    Ybuf[(size_t)bt * 4096 + idx] = Msh[(((idx >> 4) & 15) << 8) + ((idx >> 8) << 4) + (idx & 15)];
  }
  int i = tid >> 4, l = tid & 15;
  float acc[16];
  for (int g = 0; g < 16; g++) acc[g] = 0.f;
  for (int c = 0; c < 3; c++) {
    __syncthreads();
    for (int e = 0; e < 16; e++) {
      int idx = tid + e * 256;
      int jj = idx >> 8, ll = (idx >> 4) & 15, ff = idx & 15;
      float a = 0.f;
      for (int k = 0; k < 16; k++) a += Msh[jj * 256 + k * 16 + ff] * Tdsh[c * 256 + k * 16 + ll];
      Rsh[idx] = a;
    }
    __syncthreads();
    for (int a = 0; a < 3; a++) {
      float sf[16];
      #pragma unroll
      for (int f = 0; f < 16; f++) {
        float s = 0.f;
        for (int jj = 0; jj < 16; jj++) s += Tosh[a * 256 + i * 16 + jj] * Rsh[jj * 256 + l * 16 + f];
        sf[f] = s;
      }
      const float* th = &thsh[(a * 3 + c) * 256];
      #pragma unroll
      for (int g = 0; g < 16; g++) {
        float s = 0.f;
        for (int f = 0; f < 16; f++) s += sf[f] * th[f * 16 + g];
        acc[g] += s;
      }
    }
  }
  for (int g = 0; g < 16; g++)
    MG[(size_t)bt * 4096 + i * 256 + l * 16 + g] = acc[g];
}

// ---------------- generic fp32 tiled GEMM: C = A(MxK) @ W(KxN) + bias [+add] [gelu] ----------------
template <int TM, bool GELU, bool ADD>
__global__ __launch_bounds__(256) void sgemm(
    const float* __restrict__ A, const float* __restrict__ W,
    const float* __restrict__ bias, const float* __restrict__ addsrc,
    float* __restrict__ C, int M, int N, int K) {
  const int BM = TM * 16, BN = 128, BK = 16;
  __shared__ float As[BK][BM];
  __shared__ float Bs[BK][BN];
  int tid = threadIdx.x;
  int n0 = blockIdx.x * BN, m0 = blockIdx.y * BM;
  int tx = tid & 15, ty = tid >> 4;
  float acc[TM][8];
  #pragma unroll
  for (int i = 0; i < TM; i++)
    #pragma unroll
    for (int j = 0; j < 8; j++) acc[i][j] = 0.f;

  for (int k0 = 0; k0 < K; k0 += BK) {
    #pragma unroll
    for (int e = 0; e < TM; e++) {
      int idx = tid + e * 256;
      int am = idx >> 4, ak = idx & 15;
      int gm = m0 + am;
      As[ak][am] = (gm < M) ? A[(size_t)gm * K + k0 + ak] : 0.f;
    }
    #pragma unroll
    for (int e = 0; e < 8; e++) {
      int idx = tid + e * 256;
      int bk = idx >> 7, bn = idx & 127;
      Bs[bk][bn] = W[(size_t)(k0 + bk) * N + n0 + bn];
    }
    __syncthreads();
    #pragma unroll
    for (int kk = 0; kk < BK; kk++) {
      float a[TM], b[8];
      #pragma unroll
      for (int i = 0; i < TM; i++) a[i] = As[kk][ty * TM + i];
      #pragma unroll
      for (int j = 0; j < 8; j++) b[j] = Bs[kk][tx * 8 + j];
      #pragma unroll
      for (int i = 0; i < TM; i++)
        #pragma unroll
        for (int j = 0; j < 8; j++) acc[i][j] += a[i] * b[j];
    }
    __syncthreads();
  }
  #pragma unroll
  for (int i = 0; i < TM; i++) {
    int gm = m0 + ty * TM + i;
    if (gm < M) {
      #pragma unroll
      for (int j = 0; j < 8; j++) {
        int gn = n0 + tx * 8 + j;
        float v = acc[i][j] + bias[gn];
        if (GELU) v = 0.5f * v * (1.0f + erff(v * 0.70710678118654752f));
        if (ADD) v += addsrc[(size_t)gm * N + gn];
        C[(size_t)gm * N + gn] = v;
      }
    }
  }
}

// ---------------- ODAttention + sparse MA + Ms blend + xm ----------------
__global__ __launch_bounds__(256) void odattn_kernel(
    const float* __restrict__ M, const float* __restrict__ HOS, const float* __restrict__ HDS,
    const float* __restrict__ Wos, const float* __restrict__ bos,
    const float* __restrict__ Wds, const float* __restrict__ bds,
    const float* __restrict__ MG, float* __restrict__ X, float* __restrict__ xm) {
  int bt = blockIdx.x, tid = threadIdx.x;
  __shared__ float Msh[4096];
  __shared__ float Hsh[8192];
  __shared__ float Psh[2][256];   // softmax probs, [pass][i*16+j]
  __shared__ float entsh[2][16];
  __shared__ int sel[2][2];
  __shared__ float tsh[512];      // t for 2 selected origin rows: [si][k*16+l]

  for (int e = 0; e < 16; e++) Msh[tid + e * 256] = M[(size_t)bt * 4096 + tid + e * 256];

  int i = tid >> 4, j = tid & 15;
  for (int pass = 0; pass < 2; pass++) {
    const float* H  = (pass == 0 ? HOS : HDS) + (size_t)bt * 8192;
    const float* Wp = (pass == 0 ? Wos : Wds);
    const float* bp = (pass == 0 ? bos : bds);
    __syncthreads();
    for (int e = 0; e < 32; e++) Hsh[tid + e * 256] = H[tid + e * 256];
    __syncthreads();
    float s = bp[j];
    for (int p = 0; p < 512; p++) s += Hsh[i * 512 + p] * Wp[p * 16 + j];
    // row softmax + entropy within 16-lane groups
    float rm = s;
    for (int m = 8; m; m >>= 1) rm = fmaxf(rm, __shfl_xor(rm, m, 64));
    float e_ = expf(s - rm);
    float rs = e_;
    for (int m = 8; m; m >>= 1) rs += __shfl_xor(rs, m, 64);
    float p_ = e_ / rs;
    float q_ = p_ * logf(p_ + 1e-9f);
    float re = q_;
    for (int m = 8; m; m >>= 1) re += __shfl_xor(re, m, 64);
    Psh[pass][i * 16 + j] = p_;
    if (j == 0) entsh[pass][i] = -re;
  }
  __syncthreads();
  if (tid < 2) {  // two smallest entropies, ties -> smaller index (jax.lax.top_k stable)
    const float* E = entsh[tid];
    int i1 = 0; float bv1 = E[0];
    for (int r = 1; r < 16; r++) if (E[r] < bv1) { bv1 = E[r]; i1 = r; }
    int i2 = -1; float bv2 = 0.f;
    for (int r = 0; r < 16; r++) {
      if (r == i1) continue;
      if (i2 < 0 || E[r] < bv2) { bv2 = E[r]; i2 = r; }
    }
    sel[tid][0] = i1; sel[tid][1] = i2;
  }
  __syncthreads();
  // t[si][k][l] = sum_m omega[isel][m] * M[m,k,l]
  for (int e = 0; e < 2; e++) {
    int idx = tid + e * 256;
    int si = idx >> 8, kl = idx & 255;
    int isel = sel[0][si];
    float a = 0.f;
    for (int m = 0; m < 16; m++) a += Psh[0][isel * 16 + m] * Msh[m * 256 + kl];
    tsh[idx] = a;
  }
  __syncthreads();
  int n1 = i, n2 = j;
  int si = (n1 == sel[0][0]) ? 0 : (n1 == sel[0][1]) ? 1 : -1;
  bool jsel = (n2 == sel[1][0]) || (n2 == sel[1][1]);
  float lsum = 0.f;
  for (int f = 0; f < 16; f++) {
    float ma = 0.f;
    if (si >= 0 && jsel) {
      for (int l = 0; l < 16; l++) ma += tsh[si * 256 + f * 16 + l] * Psh[1][n2 * 16 + l];
    }
    float v = 0.5f * MG[(size_t)bt * 4096 + n1 * 256 + n2 * 16 + f] + 0.5f * ma;
    X[(size_t)bt * 4096 + n1 * 256 + n2 * 16 + f] = v;
    lsum += v;
  }
  float tot = block_sum256(lsum);
  if (tid == 0) xm[bt] = tot / 4096.0f;
}

// ---------------- Periodicity: detrend + linear autocorr + top-4 ----------------
__global__ void period_kernel(const float* __restrict__ xm,
                              float* __restrict__ out_periods, int* __restrict__ pmat) {
  int b = blockIdx.x, tid = threadIdx.x;
  __shared__ float xs[TT], det[TT], ac[TT];
  __shared__ float mean_s;
  if (tid < TT) xs[tid] = xm[b * TT + tid];
  __syncthreads();
  if (tid < TT) {
    float s = 0.f;
    for (int d = -12; d <= 12; d++) {
      int idx = tid + d; idx = idx < 0 ? 0 : (idx > TT - 1 ? TT - 1 : idx);
      s += xs[idx];
    }
    det[tid] = xs[tid] - s * (1.0f / 25.0f);
  }
  __syncthreads();
  if (tid == 0) {
    float s = 0.f;
    for (int t = 0; t < TT; t++) s += det[t];
    mean_s = s / (float)TT;
  }
  __syncthreads();
  if (tid < TT) det[tid] -= mean_s;
  __syncthreads();
  if (tid < TT) {
    float s = 0.f;
    for (int t = 0; t + tid < TT; t++) s += det[t] * det[t + tid];
    ac[tid] = (tid < 2) ? -1e9f : s;
  }
  __syncthreads();
  if (tid == 0) {
    bool taken[TT];
    for (int l = 0; l < TT; l++) taken[l] = false;
    for (int r = 0; r < 4; r++) {
      int bi = -1; float bv = 0.f;
      for (int l = 0; l < TT; l++) {
        if (taken[l]) continue;
        if (bi < 0 || ac[l] > bv) { bv = ac[l]; bi = l; }
      }
      taken[bi] = true;
      out_periods[b * 4 + r] = (float)bi;
      pmat[b * 4 + r] = (bi < 1) ? 1 : bi;
    }
  }
}

// ---------------- LayerNorm over D=4096 per row ----------------
__global__ __launch_bounds__(256) void ln_kernel(
    const float* __restrict__ Xin, const float* __restrict__ g,
    const float* __restrict__ be, float* __restrict__ Xout) {
  int r = blockIdx.x, tid = threadIdx.x;
  size_t base = (size_t)r * 4096;
  float xv[16];
  #pragma unroll
  for (int e = 0; e < 16; e++) xv[e] = Xin[base + e * 256 + tid];
  float s = 0.f;
  #pragma unroll
  for (int e = 0; e < 16; e++) s += xv[e];
  float mu = block_sum256(s) / 4096.0f;
  float sq = 0.f;
  #pragma unroll
  for (int e = 0; e < 16; e++) { float d = xv[e] - mu; sq += d * d; }
  float var = block_sum256(sq) / 4096.0f;
  float rstd = rsqrtf(var + 1e-5f);
  #pragma unroll
  for (int e = 0; e < 16; e++) {
    int col = e * 256 + tid;
    Xout[base + col] = (xv[e] - mu) * rstd * g[col] + be[col];
  }
}

// ---------------- period-sparse attention (one head per period) ----------------
__global__ __launch_bounds__(256) void attn_kernel(
    const float* __restrict__ Q, const float* __restrict__ Kb,
    const float* __restrict__ Vb, const int* __restrict__ pmat,
    float* __restrict__ Hb) {
  int i = blockIdx.x, h = blockIdx.y, b = blockIdx.z;
  int tid = threadIdx.x;
  int p = pmat[b * HH + h];
  int ns = i / p + 1;  // allowed j: j = i - m*p, m=0..i/p
  __shared__ float qs[HDIM];
  __shared__ float ssh[176];
  __shared__ float stats[2];
  size_t base = ((size_t)(b * TT + i) * DD) + (size_t)h * HDIM;
  for (int e = 0; e < 4; e++) qs[tid + e * 256] = Q[base + tid + e * 256];
  __syncthreads();
  int g = tid >> 4, lane = tid & 15;
  for (int m = g; m < ns; m += 16) {
    int jj = i - m * p;
    size_t kb = ((size_t)(b * TT + jj) * DD) + (size_t)h * HDIM;
    float s = 0.f;
    for (int d = lane; d < HDIM; d += 16) s += qs[d] * Kb[kb + d];
    for (int mm = 8; mm; mm >>= 1) s += __shfl_xor(s, mm, 64);
    if (lane == 0) ssh[m] = s * (1.0f / 32.0f);
  }
  __syncthreads();
  if (tid == 0) {
    float mx = ssh[0];
    for (int m = 1; m < ns; m++) mx = fmaxf(mx, ssh[m]);
    stats[0] = mx;
  }
  __syncthreads();
  if (tid < ns) ssh[tid] = expf(ssh[tid] - stats[0]);
  __syncthreads();
  if (tid == 0) {
    float sm = 0.f;
    for (int m = 0; m < ns; m++) sm += ssh[m];
    stats[1] = 1.0f / sm;
  }
  __syncthreads();
  float inv = stats[1];
  int d0 = tid * 4;
  float4 acc = make_float4(0.f, 0.f, 0.f, 0.f);
  for (int m = 0; m < ns; m++) {
    int jj = i - m * p;
    float w = ssh[m] * inv;
    const float4 v4 = *(const float4*)&Vb[((size_t)(b * TT + jj) * DD) + (size_t)h * HDIM + d0];
    acc.x += w * v4.x; acc.y += w * v4.y; acc.z += w * v4.z; acc.w += w * v4.w;
  }
  *(float4*)&Hb[base + d0] = acc;
}

// ---------------- launch ----------------
extern "C" void kernel_launch(void* const* d_in, const int* in_sizes, int n_in,
                              void* d_out, int out_size, void* d_ws, size_t ws_size,
                              hipStream_t stream) {
  (void)in_sizes; (void)n_in; (void)out_size; (void)ws_size;
  const float* M     = (const float*)d_in[0];
  const float* Lo    = (const float*)d_in[1];
  const float* Ld    = (const float*)d_in[2];
  const float* theta = (const float*)d_in[3];
  const float* Wop   = (const float*)d_in[4];
  const float* bop   = (const float*)d_in[5];
  const float* Wdp   = (const float*)d_in[6];
  const float* bdp   = (const float*)d_in[7];
  const float* Wos   = (const float*)d_in[8];
  const float* bos   = (const float*)d_in[9];
  const float* Wds   = (const float*)d_in[10];
  const float* bds   = (const float*)d_in[11];
  const float* Wq    = (const float*)d_in[12];
  const float* bq    = (const float*)d_in[13];
  const float* Wk    = (const float*)d_in[14];
  const float* bk    = (const float*)d_in[15];
  const float* Wv    = (const float*)d_in[16];
  const float* bv    = (const float*)d_in[17];
  const float* Wo    = (const float*)d_in[18];
  const float* bo    = (const float*)d_in[19];
  const float* W1    = (const float*)d_in[20];
  const float* b1    = (const float*)d_in[21];
  const float* W2    = (const float*)d_in[22];
  const float* b2    = (const float*)d_in[23];
  const float* g1    = (const float*)d_in[24];
  const float* be1   = (const float*)d_in[25];
  const float* g2    = (const float*)d_in[26];
  const float* be2   = (const float*)d_in[27];

  float* ws   = (float*)d_ws;
  float* To   = ws + OFF_TO;
  float* Td   = ws + OFF_TD;
  float* xm   = ws + OFF_XM;
  int*   pm   = (int*)(ws + OFF_PM);
  float* Ybuf = ws + OFF_Y;
  float* MGb  = ws + OFF_MG;   // later reused as attn output
  float* Xb   = ws + OFF_X;
  float* XNb  = ws + OFF_XN;
  float* Qb   = ws + OFF_Q;
  float* Kbf  = ws + OFF_K;
  float* Vbf  = ws + OFF_V;
  float* HOS  = ws + OFF_Q;    // dead before Q written
  float* HDS  = ws + OFF_V;    // dead before V written
  float* HID  = ws + OFF_Q;    // dead after attention
  float* xout = (float*)d_out;
  float* pout = xout + (size_t)BT * DD;

  cheb_kernel<<<1, 256, 0, stream>>>(Lo, Ld, To, Td);
  gcn_kernel<<<BT, 256, 0, stream>>>(M, To, Td, theta, MGb, Ybuf);
  // origin/destination projections: (10752,256)@(256,512)
  sgemm<8, false, false><<<dim3(4, 84), 256, 0, stream>>>(M,    Wop, bop, nullptr, HOS, XROWS, HDH, 256);
  sgemm<8, false, false><<<dim3(4, 84), 256, 0, stream>>>(Ybuf, Wdp, bdp, nullptr, HDS, XROWS, HDH, 256);
  odattn_kernel<<<BT, 256, 0, stream>>>(M, HOS, HDS, Wos, bos, Wds, bds, MGb, Xb, xm);
  period_kernel<<<BB, 256, 0, stream>>>(xm, pout, pm);
  ln_kernel<<<BT, 256, 0, stream>>>(Xb, g1, be1, XNb);
  sgemm<4, false, false><<<dim3(32, 11), 256, 0, stream>>>(XNb, Wq, bq, nullptr, Qb,  BT, DD, DD);
  sgemm<4, false, false><<<dim3(32, 11), 256, 0, stream>>>(XNb, Wk, bk, nullptr, Kbf, BT, DD, DD);
  sgemm<4, false, false><<<dim3(32, 11), 256, 0, stream>>>(XNb, Wv, bv, nullptr, Vbf, BT, DD, DD);
  attn_kernel<<<dim3(TT, HH, BB), 256, 0, stream>>>(Qb, Kbf, Vbf, pm, MGb);
  sgemm<4, false, true><<<dim3(32, 11), 256, 0, stream>>>(MGb, Wo, bo, Xb, Xb, BT, DD, DD);
  ln_kernel<<<BT, 256, 0, stream>>>(Xb, g2, be2, XNb);
  sgemm<8, true, false><<<dim3(128, 6), 256, 0, stream>>>(XNb, W1, b1, nullptr, HID, BT, DFF, DD);
  sgemm<4, false, true><<<dim3(32, 11), 256, 0, stream>>>(HID, W2, b2, Xb, xout, BT, DD, DFF);
}